// Round 7
// baseline (176.054 us; speedup 1.0000x reference)
//
#include <hip/hip_runtime.h>
#include <hip/hip_bf16.h>

typedef __bf16 bf16x8 __attribute__((ext_vector_type(8)));
typedef float  f32x4  __attribute__((ext_vector_type(4)));
typedef float  f32x16 __attribute__((ext_vector_type(16)));

static constexpr int S  = 64;    // DIM_S
static constexpr int C  = 8;     // DIM_C (experts)
static constexpr int HD = 256;   // hidden width

__device__ __forceinline__ unsigned short f2bf(float f) {
  __hip_bfloat16 b = __float2bfloat16(f);
  unsigned short u;
  __builtin_memcpy(&u, &b, 2);
  return u;
}

// async global->LDS DMA, 16 B per lane; lds dest = wave-uniform base + lane*16
__device__ __forceinline__ void gl2lds16(const void* g, void* l) {
  __builtin_amdgcn_global_load_lds(
      (const __attribute__((address_space(1))) unsigned int*)g,
      (__attribute__((address_space(3))) unsigned int*)l, 16, 0, 0);
}

// LDS-tiled transposes, coalesced both sides.  (unchanged, verified)
// blocks 0..511:  W2 [C][256k][256n] -> W2T bf16 [C][256n][256k]
// blocks 512..639: W1 [C][64s][256h] -> W1T bf16 [C][256h][64s]
__global__ __launch_bounds__(256) void prep_weights(
    const float* __restrict__ W1, const float* __restrict__ W2,
    unsigned short* __restrict__ W1T, unsigned short* __restrict__ W2T)
{
  __shared__ float tile[32][33];
  const int tid = threadIdx.x, cl = tid & 31, r0 = tid >> 5;
  const int b = blockIdx.x;
  if (b < 512) {
    const int c = b >> 6, t = b & 63, kt = t >> 3, nt = t & 7;
    const float* src = W2 + c * 65536;
    #pragma unroll
    for (int i = 0; i < 4; ++i) {
      int r = r0 + 8 * i;
      tile[r][cl] = src[(kt * 32 + r) * 256 + nt * 32 + cl];
    }
    __syncthreads();
    unsigned short* dst = W2T + c * 65536;
    #pragma unroll
    for (int i = 0; i < 4; ++i) {
      int r = r0 + 8 * i;
      dst[(nt * 32 + r) * 256 + kt * 32 + cl] = f2bf(tile[cl][r]);
    }
  } else {
    const int bb = b - 512;
    const int c = bb >> 4, t = bb & 15, st2 = t >> 3, ht = t & 7;
    const float* src = W1 + c * 16384;
    #pragma unroll
    for (int i = 0; i < 4; ++i) {
      int r = r0 + 8 * i;
      tile[r][cl] = src[(st2 * 32 + r) * 256 + ht * 32 + cl];
    }
    __syncthreads();
    unsigned short* dst = W1T + c * 16384;
    #pragma unroll
    for (int i = 0; i < 4; ++i) {
      int r = r0 + 8 * i;
      dst[(ht * 32 + r) * 64 + st2 * 32 + cl] = f2bf(tile[cl][r]);
    }
  }
}

// One block: 256 batch rows x 1 expert; 4 waves x 64 rows.
// R0's verified skeleton (chunked W2 DMA ping-pong, per-64-hidden sT
// transpose cadence) converted to mfma_f32_32x32x16_bf16 (same FLOP, half
// the MFMA instructions) with R2-verified 32x32 lane mappings:
//   A/B operand: m|n = lane&31, k = 8*(lane>>5)+e
//   C/D:         col = lane&31, row = (reg&3)+8*(reg>>2)+4*(lane>>5)
// st staged directly into registers (no sU-as-st phase, barrier #1 gone);
// W2 DMA prologue issues at kernel start and hides under phase 1.
__global__ __launch_bounds__(256, 2) void moe_fused(
    const float* __restrict__ st,
    const unsigned short* __restrict__ W1T,
    const unsigned short* __restrict__ W2T,
    const float* __restrict__ b1,
    const float* __restrict__ b2,
    const float* __restrict__ W3,
    const float* __restrict__ b3,
    float* __restrict__ out)
{
  constexpr int LDT = 72;   // sT pitch: 64 + 8 pad bf16 (144 B rows, 16B-mult)

  __shared__ __align__(16) unsigned short sT[256 * LDT];    // 36864 B transpose buf
  __shared__ __align__(16) unsigned short sU[2 * 32 * 256]; // 32768 B W2 ping-pong

  const int tid  = threadIdx.x;
  const int lane = tid & 63;
  const int wv   = tid >> 6;          // wave -> batch rows [wv*64, wv*64+64)
  const int l31  = lane & 31;
  const int h5   = lane >> 5;
  const int c    = blockIdx.x >> 8;
  const int row0 = (blockIdx.x & 255) * 256;
  const int wrow = row0 + wv * 64;

  const unsigned short* W1c = W1T + c * HD * S;
  const unsigned short* W2c = W2T + c * HD * HD;

  // ---- DMA prologue: W2 chunks 0,1 into sU (issued FIRST; latency hides
  // under all of phase 1; drained by the pre-phase-2 barrier) ----
  #pragma unroll
  for (int pc = 0; pc < 2; ++pc) {
    unsigned short* buf = sU + pc * (32 * 256);
    #pragma unroll
    for (int i = 0; i < 4; ++i) {
      const int b2i = wv * 4 + i;            // 1KB unit (2 rows)
      const int r   = b2i * 2 + (lane >> 5); // local row 0..31
      const int j   = (lane & 31) ^ (r & 7); // logical granule
      gl2lds16(W2c + (pc * 32 + r) * 256 + j * 8, buf + b2i * 512);
    }
  }

  // ---- per-block scalars ----
  float b2v[8], w3v[8];
  #pragma unroll
  for (int ch = 0; ch < 8; ++ch) {
    b2v[ch] = b2[c * HD + ch * 32 + l31];
    w3v[ch] = W3[c * HD + ch * 32 + l31];
  }
  const float bb3 = b3[c];

  // ---- phase-1 B frags: wave's 64 st rows (fp32 -> bf16 via cvt_pk),
  // straight from global (n = batch = l31, k = s = ks*16+8*h5+e) ----
  bf16x8 bB[4][2];   // [ks][nt]
  #pragma unroll
  for (int nt = 0; nt < 2; ++nt)
    #pragma unroll
    for (int ks = 0; ks < 4; ++ks) {
      const float* rp = st + (size_t)(wrow + nt * 32 + l31) * S + ks * 16 + h5 * 8;
      float4 x = *reinterpret_cast<const float4*>(rp);
      float4 y = *reinterpret_cast<const float4*>(rp + 4);
      union { bf16x8 v; unsigned u[4]; } pk;
      __asm__("v_cvt_pk_bf16_f32 %0, %1, %2" : "=v"(pk.u[0]) : "v"(x.x), "v"(x.y));
      __asm__("v_cvt_pk_bf16_f32 %0, %1, %2" : "=v"(pk.u[1]) : "v"(x.z), "v"(x.w));
      __asm__("v_cvt_pk_bf16_f32 %0, %1, %2" : "=v"(pk.u[2]) : "v"(y.x), "v"(y.y));
      __asm__("v_cvt_pk_bf16_f32 %0, %1, %2" : "=v"(pk.u[3]) : "v"(y.z), "v"(y.w));
      bB[ks][nt] = pk.v;
    }

  // ---- phase 1: h1^T = W1^T @ st^T, one 64-hidden group at a time ----
  bf16x8 aF[2][16];   // [rt][k-step]: phase-2 A-frags (m=batch l31, k=hidden)
  #pragma unroll
  for (int grp = 0; grp < 4; ++grp) {
    #pragma unroll
    for (int mt2 = 0; mt2 < 2; ++mt2) {
      const int mt = grp * 2 + mt2;   // hidden 32-tile
      bf16x8 aW[4];
      #pragma unroll
      for (int ks = 0; ks < 4; ++ks)
        aW[ks] = *reinterpret_cast<const bf16x8*>(
            W1c + (size_t)(mt * 32 + l31) * S + ks * 16 + h5 * 8);

      union { f32x4 q[4]; f32x16 v; } bu;   // b1 C-in (D rows 8g+4h5+j)
      #pragma unroll
      for (int g = 0; g < 4; ++g)
        bu.q[g] = *reinterpret_cast<const f32x4*>(
            b1 + c * HD + mt * 32 + 8 * g + 4 * h5);

      __builtin_amdgcn_s_setprio(1);
      f32x16 acc0 = __builtin_amdgcn_mfma_f32_32x32x16_bf16(aW[0], bB[0][0], bu.v, 0, 0, 0);
      f32x16 acc1 = __builtin_amdgcn_mfma_f32_32x32x16_bf16(aW[0], bB[0][1], bu.v, 0, 0, 0);
      #pragma unroll
      for (int ks = 1; ks < 4; ++ks) {
        acc0 = __builtin_amdgcn_mfma_f32_32x32x16_bf16(aW[ks], bB[ks][0], acc0, 0, 0, 0);
        acc1 = __builtin_amdgcn_mfma_f32_32x32x16_bf16(aW[ks], bB[ks][1], acc1, 0, 0, 0);
      }
      __builtin_amdgcn_s_setprio(0);

      // epilogue: relu (b1 already in C-in), cvt_pk -> 8B writes into the
      // wave-private 64-col sT region (cols mt2*32 + 8g+4h5 .. +3)
      #pragma unroll
      for (int nt = 0; nt < 2; ++nt) {
        const f32x16& A = nt ? acc1 : acc0;
        const int rbase = (wv * 64 + nt * 32 + l31) * LDT + mt2 * 32;
        #pragma unroll
        for (int g = 0; g < 4; ++g) {
          float v0 = A[4*g+0]; v0 = v0 > 0.f ? v0 : 0.f;
          float v1 = A[4*g+1]; v1 = v1 > 0.f ? v1 : 0.f;
          float v2 = A[4*g+2]; v2 = v2 > 0.f ? v2 : 0.f;
          float v3 = A[4*g+3]; v3 = v3 > 0.f ? v3 : 0.f;
          uint2 pk;
          __asm__("v_cvt_pk_bf16_f32 %0, %1, %2" : "=v"(pk.x) : "v"(v0), "v"(v1));
          __asm__("v_cvt_pk_bf16_f32 %0, %1, %2" : "=v"(pk.y) : "v"(v2), "v"(v3));
          *reinterpret_cast<uint2*>(sT + rbase + 8 * g + 4 * h5) = pk;
        }
      }
    }
    __asm__ __volatile__("s_waitcnt lgkmcnt(0)" ::: "memory");
    #pragma unroll
    for (int rt = 0; rt < 2; ++rt)
      #pragma unroll
      for (int s2 = 0; s2 < 4; ++s2)
        aF[rt][grp * 4 + s2] = *reinterpret_cast<const bf16x8*>(
            sT + (wv * 64 + rt * 32 + l31) * LDT + s2 * 16 + h5 * 8);
    __asm__ __volatile__("s_waitcnt lgkmcnt(0)" ::: "memory");  // WAR guard
  }

  __syncthreads();   // barrier: drains W2 DMA (vmcnt) -> chunks 0,1 landed

  // ---- phase 2+3: d = relu(h1 @ W2 + b2) . W3, chunk ping-pong ----
  float dacc0[16], dacc1[16];
  #pragma unroll
  for (int r = 0; r < 16; ++r) { dacc0[r] = 0.f; dacc1[r] = 0.f; }

  #pragma unroll
  for (int ch = 0; ch < 8; ++ch) {
    const unsigned short* buf = sU + (ch & 1) * (32 * 256);

    // b2 folded into C-in: D col = n = l31 -> splat across all regs
    f32x16 b2i;
    #pragma unroll
    for (int r = 0; r < 16; ++r) b2i[r] = b2v[ch];

    f32x16 acc0, acc1;
    #pragma unroll
    for (int stp = 0; stp < 16; ++stp) {
      const int j = stp * 2 + h5;          // k-granule of this 16-k step
      bf16x8 bF = *reinterpret_cast<const bf16x8*>(
          buf + l31 * 256 + ((j ^ (l31 & 7)) << 3));
      __builtin_amdgcn_s_setprio(1);
      if (stp == 0) {
        acc0 = __builtin_amdgcn_mfma_f32_32x32x16_bf16(aF[0][0], bF, b2i, 0, 0, 0);
        acc1 = __builtin_amdgcn_mfma_f32_32x32x16_bf16(aF[1][0], bF, b2i, 0, 0, 0);
      } else {
        acc0 = __builtin_amdgcn_mfma_f32_32x32x16_bf16(aF[0][stp], bF, acc0, 0, 0, 0);
        acc1 = __builtin_amdgcn_mfma_f32_32x32x16_bf16(aF[1][stp], bF, acc1, 0, 0, 0);
      }
      __builtin_amdgcn_s_setprio(0);
    }

    // fused epilogue: relu(h2) dot W3 (bias already in C-in)
    #pragma unroll
    for (int r = 0; r < 16; ++r) {
      float v0 = acc0[r]; v0 = v0 > 0.f ? v0 : 0.f; dacc0[r] += v0 * w3v[ch];
      float v1 = acc1[r]; v1 = v1 > 0.f ? v1 : 0.f; dacc1[r] += v1 * w3v[ch];
    }

    __syncthreads();   // readers of buf[ch&1] done; drains chunk ch+1's DMA
    if (ch < 6) {      // refill freed buffer with chunk ch+2
      unsigned short* nbuf = sU + (ch & 1) * (32 * 256);
      #pragma unroll
      for (int i = 0; i < 4; ++i) {
        const int b2i2 = wv * 4 + i;
        const int r    = b2i2 * 2 + (lane >> 5);
        const int j    = (lane & 31) ^ (r & 7);
        gl2lds16(W2c + ((ch + 2) * 32 + r) * 256 + j * 8, nbuf + b2i2 * 512);
      }
    }
  }

  // ---- reduce over the 32 n-lanes (xor net stays within each half) ----
  #pragma unroll
  for (int r = 0; r < 16; ++r) {
    float v0 = dacc0[r], v1 = dacc1[r];
    v0 += __shfl_xor(v0, 1);  v1 += __shfl_xor(v1, 1);
    v0 += __shfl_xor(v0, 2);  v1 += __shfl_xor(v1, 2);
    v0 += __shfl_xor(v0, 4);  v1 += __shfl_xor(v1, 4);
    v0 += __shfl_xor(v0, 8);  v1 += __shfl_xor(v1, 8);
    v0 += __shfl_xor(v0, 16); v1 += __shfl_xor(v1, 16);
    dacc0[r] = v0; dacc1[r] = v1;
  }

  if (l31 == 0) {   // lanes 0 and 32 write (h5 splits the row groups)
    #pragma unroll
    for (int r = 0; r < 16; ++r) {
      const int rr = (r & 3) + 8 * (r >> 2) + 4 * h5;   // D row within 32-tile
      out[(size_t)(wrow + rr) * C + c]      = dacc0[r] + bb3;
      out[(size_t)(wrow + 32 + rr) * C + c] = dacc1[r] + bb3;
    }
  }
}

extern "C" void kernel_launch(void* const* d_in, const int* in_sizes, int n_in,
                              void* d_out, int out_size, void* d_ws, size_t ws_size,
                              hipStream_t stream)
{
  const float* st = (const float*)d_in[0];
  const float* W1 = (const float*)d_in[1];
  const float* b1 = (const float*)d_in[2];
  const float* W2 = (const float*)d_in[3];
  const float* b2 = (const float*)d_in[4];
  const float* W3 = (const float*)d_in[5];
  const float* b3 = (const float*)d_in[6];
  float* out = (float*)d_out;

  unsigned short* W1T = (unsigned short*)d_ws;         // 131072 bf16
  unsigned short* W2T = W1T + C * HD * S;              // 524288 bf16

  prep_weights<<<dim3(640), dim3(256), 0, stream>>>(W1, W2, W1T, W2T);
  moe_fused<<<dim3(2048), dim3(256), 0, stream>>>(st, W1T, W2T, b1, b2, W3, b3, out);
}